// Round 5
// baseline (653.561 us; speedup 1.0000x reference)
//
#include <hip/hip_runtime.h>
#include <math.h>
#include <utility>

#define NLEADS 61
#define AIL __attribute__((always_inline))

// Guaranteed-unroll helper: indices are compile-time constants -> SROA to regs.
template <int... Is, typename F>
__device__ __forceinline__ void sf_(std::integer_sequence<int, Is...>, F&& f) {
    (f(std::integral_constant<int, Is>{}), ...);
}
template <int N, typename F>
__device__ __forceinline__ void static_for(F&& f) {
    sf_(std::make_integer_sequence<int, N>{}, (F&&)f);
}

__device__ __forceinline__ float4 ld4(const float* p) { return *(const float4*)p; }
__device__ __forceinline__ float2 ld2(const float* p) { return *(const float2*)p; }

template <int C> __device__ __forceinline__ float f4c(float4 v) {
    if constexpr (C == 0) return v.x;
    else if constexpr (C == 1) return v.y;
    else if constexpr (C == 2) return v.z;
    else return v.w;
}
template <int C> __device__ __forceinline__ float f6(float4 a, float2 b) {
    if constexpr (C < 4) return f4c<C>(a);
    else if constexpr (C == 4) return b.x;
    else return b.y;
}
template <int K> __device__ __forceinline__ float w12(float4 w0, float4 w1, float4 w2) {
    if constexpr (K < 4) return f4c<K>(w0);
    else if constexpr (K < 8) return f4c<K - 4>(w1);
    else return f4c<K - 8>(w2);
}

// LDS (floats):
//  A[0..4351]  : h1p HALF buffer [4ic][16][68] (col c at idx c+1; idx 0,64,65 zero)
//                after conv2: sh3@0[256], spart@256[256], shf@512[64], slog@580[3],
//                sfc@600[195]
//  H2[0..1287] : h2p[16][4][20] (col-padded) + 8 guard
// Total 5640 floats = 22560 B -> 6 blocks/CU (24 waves) with VGPR <= 85.
__global__ __launch_bounds__(256, 6)
void lead_cnn_kernel(const float* __restrict__ x,
                     const float* __restrict__ w1g, const float* __restrict__ b1g,
                     const float* __restrict__ w2g, const float* __restrict__ b2g,
                     const float* __restrict__ w3g, const float* __restrict__ b3g,
                     const float* __restrict__ w4g, const float* __restrict__ b4g,
                     const float* __restrict__ fcwg, const float* __restrict__ fcbg,
                     float* __restrict__ preds)
{
    __shared__ __align__(16) float smem[5640];
    float* const A  = smem;
    float* const H2 = smem + 4352;

    const int t = threadIdx.x;
    const int b = blockIdx.x;
    const int l = blockIdx.y;

    const float* xg  = x + ((size_t)b * NLEADS + l) * 8000;
    const float* w1l = w1g + l * 96;       // wave-uniform -> s_load
    const float* b1l = b1g + l * 8;

    // ---- zero LDS pads once (persist; never overwritten) ----
    if (t < 192) {                       // h1p-half pads: idx 0, 64, 65 per (ic,row)
        const int ic = t / 48, j = t - ic * 48;
        const int r = j / 3, k = j - r * 3;
        A[ic * 1088 + r * 68 + ((k == 0) ? 0 : (63 + k))] = 0.f;
    }
    if (t >= 128) {                      // H2 pads: idx 0 and 17 per (ch,row)
        const int i = t - 128;
        const int ch = i >> 3, r = (i >> 1) & 3;
        H2[ch * 80 + r * 20 + ((i & 1) ? 17 : 0)] = 0.f;
    }

    // ===== conv1 (8,1,3,4) s(1,2) p(1,2) + pool2 + relu, x direct from HBM ========
    // lane -> pw (0..62 valid, 63 garbage), wave -> row-group; ph = rg*4 + it.
    const int pw = t & 63;
    const int rg = t >> 6;
    const int cm = (pw <= 62) ? 4 * pw : 248;                  // clamped in-bounds
    const int c1 = (pw == 0) ? 0 : ((pw <= 62) ? 4 * pw - 2 : 248);
    const int c3 = (pw >= 62) ? 248 : 4 * pw + 2;
    const bool lok = (pw > 0);
    const bool rok = (pw < 62);

    float acc1[32];   // [it*8+oc], constexpr-indexed
    static_for<4>([&](auto IT) AIL {
        constexpr int it = IT.value;
        const int ph = rg * 4 + it;
        float xw[24];                      // [r*6+c]
        static_for<4>([&](auto R) AIL {
            constexpr int r = R.value;
            const int ih = 2 * ph - 1 + r;
            const int rr = (ih < 0) ? 0 : ((ih > 31) ? 31 : ih);
            const bool rowok = ((unsigned)ih < 32u);
            const float* xr = xg + rr * 250;
            const float2 e0 = ld2(xr + c1);
            const float2 e1 = ld2(xr + cm);
            const float2 e2 = ld2(xr + c3);
            const bool okl = rowok & lok, okr = rowok & rok;
            xw[r*6+0] = okl ? e0.x : 0.f;
            xw[r*6+1] = okl ? e0.y : 0.f;
            xw[r*6+2] = rowok ? e1.x : 0.f;
            xw[r*6+3] = rowok ? e1.y : 0.f;
            xw[r*6+4] = okr ? e2.x : 0.f;
            xw[r*6+5] = okr ? e2.y : 0.f;
        });
        static_for<8>([&](auto OC) AIL {
            constexpr int oc = OC.value;
            const float4 q0 = ld4(w1l + oc * 12);      // uniform -> SGPR
            const float4 q1 = ld4(w1l + oc * 12 + 4);
            const float4 q2 = ld4(w1l + oc * 12 + 8);
            float p00 = 0.f, p01 = 0.f, p10 = 0.f, p11 = 0.f;
            static_for<3>([&](auto KH) AIL {
                constexpr int kh = KH.value;
                static_for<4>([&](auto KW) AIL {
                    constexpr int kw = KW.value;
                    const float wv = w12<kh * 4 + kw>(q0, q1, q2);
                    p00 = fmaf(wv, xw[kh * 6 + kw], p00);
                    p01 = fmaf(wv, xw[kh * 6 + kw + 2], p01);
                    p10 = fmaf(wv, xw[(kh + 1) * 6 + kw], p10);
                    p11 = fmaf(wv, xw[(kh + 1) * 6 + kw + 2], p11);
                });
            });
            const float m = fmaxf(fmaxf(p00, p01), fmaxf(p10, p11));
            acc1[it * 8 + oc] = fmaxf(m + b1l[oc], 0.f);
        });
    });

    // ---- store h1p HALF 1 (oc 0..3) ----
    if (pw < 63) {
        static_for<4>([&](auto IT) AIL {
            const int base = (rg * 4 + IT.value) * 68 + pw + 1;
            static_for<4>([&](auto OC) AIL {
                A[OC.value * 1088 + base] = acc1[IT.value * 8 + OC.value];
            });
        });
    }
    __syncthreads();

    // ===== conv2 (16,8,4,3) s(2,2) p(1,1) + pool2 + relu, K split in 2 halves =====
    const int s2 = t & 63;
    const int ogu = __builtin_amdgcn_readfirstlane(t >> 6);   // wave-uniform
    const int ph2 = s2 >> 4, pw2 = s2 & 15;
    float a2[16];
    static_for<16>([&](auto I) AIL { a2[I.value] = 0.f; });

    auto conv2_half = [&](int wic0) AIL {
        static_for<4>([&](auto ICL) AIL {
            constexpr int icl = ICL.value;
            float4 ya[6]; float2 yb[6];
            static_for<6>([&](auto R) AIL {
                constexpr int r = R.value;
                const int Rr = 4 * ph2 - 1 + r;
                const int rr = (Rr < 0) ? 0 : ((Rr > 15) ? 15 : Rr);
                const float* hp = A + icl * 1088 + rr * 68 + 4 * pw2;  // 16B-aligned
                float4 va = ld4(hp);
                float2 vb = ld2(hp + 4);
                if constexpr (r == 0 || r == 5) {      // only rows that can be OOB
                    const bool ok = ((unsigned)Rr < 16u);
                    va.x = ok ? va.x : 0.f; va.y = ok ? va.y : 0.f;
                    va.z = ok ? va.z : 0.f; va.w = ok ? va.w : 0.f;
                    vb.x = ok ? vb.x : 0.f; vb.y = ok ? vb.y : 0.f;
                }
                ya[r] = va; yb[r] = vb;
            });
            static_for<4>([&](auto OL) AIL {
                constexpr int ol = OL.value;
                const float* wp = w2g
                    + ((size_t)((l * 16 + ogu * 4 + ol) * 8 + wic0 + icl)) * 12;
                const float4 q0 = ld4(wp), q1 = ld4(wp + 4), q2 = ld4(wp + 8);
                static_for<4>([&](auto KH) AIL {
                    constexpr int kh = KH.value;
                    static_for<3>([&](auto KW) AIL {
                        constexpr int kw = KW.value;
                        const float wv = w12<kh * 3 + kw>(q0, q1, q2);
                        a2[ol*4+0] = fmaf(wv, f6<kw>(ya[kh], yb[kh]), a2[ol*4+0]);
                        a2[ol*4+1] = fmaf(wv, f6<kw + 2>(ya[kh], yb[kh]), a2[ol*4+1]);
                        a2[ol*4+2] = fmaf(wv, f6<kw>(ya[kh + 2], yb[kh + 2]), a2[ol*4+2]);
                        a2[ol*4+3] = fmaf(wv, f6<kw + 2>(ya[kh + 2], yb[kh + 2]), a2[ol*4+3]);
                    });
                });
            });
        });
    };

    conv2_half(0);
    __syncthreads();                 // half-1 LDS reads complete

    // ---- store h1p HALF 2 (oc 4..7) into the same slots ----
    if (pw < 63) {
        static_for<4>([&](auto IT) AIL {
            const int base = (rg * 4 + IT.value) * 68 + pw + 1;
            static_for<4>([&](auto OC) AIL {
                A[OC.value * 1088 + base] = acc1[IT.value * 8 + 4 + OC.value];
            });
        });
    }
    __syncthreads();

    conv2_half(4);
    static_for<4>([&](auto OL) AIL {
        constexpr int ol = OL.value;
        const int oc = ogu * 4 + ol;
        const float m = fmaxf(fmaxf(a2[ol*4+0], a2[ol*4+1]),
                              fmaxf(a2[ol*4+2], a2[ol*4+3]));
        H2[oc * 80 + ph2 * 20 + pw2 + 1] = fmaxf(m + b2g[l * 16 + oc], 0.f);
    });
    __syncthreads();

    // ===== conv3 (32,16,3,4) s(1,2) p(1,1) + pool2 + relu -> sh3 (32,2,4) ==========
    {
        const int oc3 = t >> 3, s3 = t & 7;
        const int ph3 = s3 >> 2, pw3 = s3 & 3;
        const float* w3l = w3g + (size_t)l * 6144 + oc3 * 192;
        const float b3v = b3g[l * 32 + oc3];
        float a30 = 0.f, a31 = 0.f, a32 = 0.f, a33 = 0.f;
        static_for<16>([&](auto IC) AIL {
            constexpr int ic = IC.value;
            float4 za[4]; float2 zb[4];
            static_for<4>([&](auto R) AIL {
                constexpr int r = R.value;
                const int Rr = 2 * ph3 - 1 + r;
                const int rr = (Rr < 0) ? 0 : ((Rr > 3) ? 3 : Rr);
                const float* zp = H2 + ic * 80 + rr * 20 + 4 * pw3;   // 16B-aligned
                float4 va = ld4(zp);
                float2 vb = ld2(zp + 4);
                if constexpr (r == 0 || r == 3) {
                    const bool ok = ((unsigned)Rr < 4u);
                    va.x = ok ? va.x : 0.f; va.y = ok ? va.y : 0.f;
                    va.z = ok ? va.z : 0.f; va.w = ok ? va.w : 0.f;
                    vb.x = ok ? vb.x : 0.f; vb.y = ok ? vb.y : 0.f;
                }
                za[r] = va; zb[r] = vb;
            });
            const float4 q0 = ld4(w3l + ic * 12);
            const float4 q1 = ld4(w3l + ic * 12 + 4);
            const float4 q2 = ld4(w3l + ic * 12 + 8);
            static_for<3>([&](auto KH) AIL {
                constexpr int kh = KH.value;
                static_for<4>([&](auto KW) AIL {
                    constexpr int kw = KW.value;
                    const float wv = w12<kh * 4 + kw>(q0, q1, q2);
                    a30 = fmaf(wv, f6<kw>(za[kh], zb[kh]), a30);
                    a31 = fmaf(wv, f6<kw + 2>(za[kh], zb[kh]), a31);
                    a32 = fmaf(wv, f6<kw>(za[kh + 1], zb[kh + 1]), a32);
                    a33 = fmaf(wv, f6<kw + 2>(za[kh + 1], zb[kh + 1]), a33);
                });
            });
        });
        const float m = fmaxf(fmaxf(a30, a31), fmaxf(a32, a33));
        A[oc3 * 8 + s3] = fmaxf(m + b3v, 0.f);    // sh3; h1p region is dead
    }
    __syncthreads();

    // ===== conv4 (64,32,2,4) VALID -> (64,) + fc-weight staging ====================
    {
        if (t < 192) A[600 + t] = fcwg[l * 192 + t];
        else if (t < 195) A[600 + t] = fcbg[l * 3 + (t - 192)];

        const int oc4 = t >> 2, part = t & 3;
        const float* w4p = w4g + (size_t)l * 16384 + oc4 * 256 + part * 64;
        float s4 = 0.f;
        static_for<8>([&](auto J) AIL {
            constexpr int j = J.value;
            const float4 wa = ld4(w4p + j * 8);
            const float4 wb = ld4(w4p + j * 8 + 4);
            const float* xx = A + (part * 8 + j) * 8;
            const float4 xA = ld4(xx), xB = ld4(xx + 4);
            s4 = fmaf(wa.x, xA.x, s4); s4 = fmaf(wa.y, xA.y, s4);
            s4 = fmaf(wa.z, xA.z, s4); s4 = fmaf(wa.w, xA.w, s4);
            s4 = fmaf(wb.x, xB.x, s4); s4 = fmaf(wb.y, xB.y, s4);
            s4 = fmaf(wb.z, xB.z, s4); s4 = fmaf(wb.w, xB.w, s4);
        });
        A[256 + part * 64 + oc4] = s4;            // spart
    }
    __syncthreads();
    if (t < 64)
        A[512 + t] = A[256 + t] + A[320 + t] + A[384 + t] + A[448 + t]
                   + b4g[l * 64 + t];             // shf
    __syncthreads();

    // ===== FC (3x64) + softmax =====================================================
    if (t < 3) {
        float s = A[792 + t];                     // fcb
        static_for<64>([&](auto I) AIL {
            s = fmaf(A[600 + t * 64 + I.value], A[512 + I.value], s);
        });
        A[580 + t] = s;                           // slog
    }
    __syncthreads();
    if (t == 0) {
        const float a0 = A[580], a1 = A[581], a2v = A[582];
        const float m = fmaxf(a0, fmaxf(a1, a2v));
        const float e0 = expf(a0 - m), e1 = expf(a1 - m), e2 = expf(a2v - m);
        const float inv = 1.f / (e0 + e1 + e2);
        float* pr = preds + ((size_t)b * NLEADS + l) * 3;
        pr[0] = e0 * inv; pr[1] = e1 * inv; pr[2] = e2 * inv;
    }
}

// Cross-lead multiplicative fusion loss. One thread per (b, class).
__global__ void fusion_loss_kernel(const float* __restrict__ preds,
                                   float* __restrict__ out, int B)
{
    const int idx = blockIdx.x * blockDim.x + threadIdx.x;
    if (idx >= B * 3) return;
    const int b = idx / 3;
    const int c = idx - 3 * b;
    const float* p = preds + (size_t)b * (NLEADS * 3) + c;
    float S = 0.f;                                // log prod(1-pj)
    for (int j = 0; j < NLEADS; ++j) S += logf(1.f - p[j * 3]);
    const float be = 2.0f / 60.0f;
    float loss = 0.f;
    for (int j = 0; j < NLEADS; ++j) {
        const float pj = p[j * 3];
        loss += expf(be * (S - logf(1.f - pj))) * logf(pj);
    }
    out[idx] = -loss;
}

extern "C" void kernel_launch(void* const* d_in, const int* in_sizes, int n_in,
                              void* d_out, int out_size, void* d_ws, size_t ws_size,
                              hipStream_t stream)
{
    const float* x   = (const float*)d_in[0];
    const float* w1  = (const float*)d_in[1];
    const float* b1  = (const float*)d_in[2];
    const float* w2  = (const float*)d_in[3];
    const float* b2  = (const float*)d_in[4];
    const float* w3  = (const float*)d_in[5];
    const float* b3  = (const float*)d_in[6];
    const float* w4  = (const float*)d_in[7];
    const float* b4  = (const float*)d_in[8];
    const float* fcw = (const float*)d_in[9];
    const float* fcb = (const float*)d_in[10];

    const int B = in_sizes[0] / (NLEADS * 32 * 250);   // 128
    float* preds = (float*)d_ws;                        // B*61*3 floats

    dim3 grid(B, NLEADS);
    hipLaunchKernelGGL(lead_cnn_kernel, grid, dim3(256), 0, stream,
                       x, w1, b1, w2, b2, w3, b3, w4, b4, fcw, fcb, preds);

    const int total = B * 3;
    hipLaunchKernelGGL(fusion_loss_kernel, dim3((total + 255) / 256), dim3(256),
                       0, stream, preds, (float*)d_out, B);
}